// Round 8
// baseline (11444.540 us; speedup 1.0000x reference)
//
#include <hip/hip_runtime.h>
#include <cstdint>
#include <cstddef>

#define H 512
#define SS 20
#define BB 16
#define LL 30
#define NN 6
#define TT 20
#define VT 30000
#define MROWS 1824   /* N*B*(T-1) */
#define NSTEPS 114   /* N*(T-1) */
#define MPAD 1856    /* 29*64 */
#define NT2 120      /* 8 chunks * 15 tiles of 256 */
#define UBLK 16      /* sequential-role blocks (one per batch element) */
#define NV 232       /* vocab-role blocks = 29 mt * 8 chunks */
#define MEGA 248

#define SCOPE_AGENT __HIP_MEMORY_SCOPE_AGENT

typedef __attribute__((ext_vector_type(8))) short bf16x8;
typedef __attribute__((ext_vector_type(4))) float f32x4;

__device__ __forceinline__ float sigmoidf_(float x) { return 1.f / (1.f + expf(-x)); }
__device__ __forceinline__ float b2f(ushort u) { return __uint_as_float(((uint32_t)u) << 16); }
__device__ __forceinline__ ushort f2b_rne(float f) {
  uint32_t u = __float_as_uint(f);
  return (ushort)((u + 0x7fffu + ((u >> 16) & 1u)) >> 16);
}
__device__ __forceinline__ void ast_u32(uint* p, uint v) {
  __hip_atomic_store(p, v, __ATOMIC_RELAXED, SCOPE_AGENT);
}
__device__ __forceinline__ uint ald_u32(const uint* p) {
  return __hip_atomic_load(p, __ATOMIC_RELAXED, SCOPE_AGENT);
}

// fence-minimal barrier among vocab blocks (R7-validated)
__device__ __forceinline__ void sbar(uint* flags, int slot, int nblk, uint phase)
{
  __syncthreads();
  if (threadIdx.x == 0) {
    __builtin_amdgcn_fence(__ATOMIC_RELEASE, "agent");
    ast_u32(&flags[slot * 16], phase);
  }
  if ((int)threadIdx.x < nblk) {
    while (ald_u32(&flags[threadIdx.x * 16]) < phase)
      __builtin_amdgcn_s_sleep(1);
  }
  __syncthreads();
  if (threadIdx.x == 0)
    __builtin_amdgcn_fence(__ATOMIC_ACQUIRE, "agent");
  __syncthreads();
}

// ---------------------------------------------------------------------------
// prep: token gathers -> bf16 A matrices; weight matrices f32 -> bf16
// ---------------------------------------------------------------------------
struct PrepP {
  const int* articles; const int* summaries;
  const float* emb_src; const float* emb_tgt;
  const float* we_Wi; const float* wd_Wi; const float* we_Wh;
  const float* se_Wi; const float* se_Wh; const float* W_feat;
  const float* wd_Wh; const float* sd_Wi; const float* sd_Wh;
  const float* attn_Wh; const float* W_out;
  ushort* A_we; ushort* A_wd;
  ushort* weWi; ushort* wdWi; ushort* weWh;
  ushort* seWi; ushort* seWh; ushort* wfeat;
  ushort* wdWh; ushort* sdWi; ushort* sdWh;
  ushort* attnWh; ushort* Wout;
};

__device__ __forceinline__ void conv_f2b(const float* __restrict__ src,
                                         ushort* __restrict__ dst, int n4,
                                         int t0, int stride)
{
  for (int i = t0; i < n4; i += stride) {
    float4 v = reinterpret_cast<const float4*>(src)[i];
    ushort4 o;
    o.x = f2b_rne(v.x); o.y = f2b_rne(v.y);
    o.z = f2b_rne(v.z); o.w = f2b_rne(v.w);
    reinterpret_cast<ushort4*>(dst)[i] = o;
  }
}

__global__ __launch_bounds__(256) void prep_kernel(PrepP P)
{
  const int t0 = blockIdx.x * 256 + threadIdx.x;
  const int stride = gridDim.x * 256;
  for (int i = t0; i < SS * BB * LL * H; i += stride) {
    int m = i >> 9, k = i & 511;
    int l = m / (SS * BB), sb = m % (SS * BB);
    int tok = P.articles[sb * LL + l];
    P.A_we[i] = f2b_rne(P.emb_src[(size_t)tok * H + k]);
  }
  for (int i = t0; i < MROWS * H; i += stride) {
    int m = i >> 9, k = i & 511;
    int stp = m >> 4, b = m & 15;
    int n = stp / (TT - 1), t = stp % (TT - 1);
    int tok = P.summaries[(n * BB + b) * TT + t];
    P.A_wd[i] = f2b_rne(P.emb_tgt[(size_t)tok * H + k]);
  }
  const int Q = 4 * H * H / 4;
  conv_f2b(P.we_Wi, P.weWi, Q, t0, stride);
  conv_f2b(P.wd_Wi, P.wdWi, Q, t0, stride);
  conv_f2b(P.we_Wh, P.weWh, Q, t0, stride);
  conv_f2b(P.se_Wi, P.seWi, Q, t0, stride);
  conv_f2b(P.se_Wh, P.seWh, Q, t0, stride);
  conv_f2b(P.wd_Wh, P.wdWh, Q, t0, stride);
  conv_f2b(P.sd_Wi, P.sdWi, Q, t0, stride);
  conv_f2b(P.sd_Wh, P.sdWh, Q, t0, stride);
  conv_f2b(P.W_feat, P.wfeat, H * H / 4, t0, stride);
  conv_f2b(P.attn_Wh, P.attnWh, H * H / 4, t0, stride);
  conv_f2b(P.W_out, P.Wout, H * 2 * H / 4, t0, stride);
}

// ---------------------------------------------------------------------------
// bf16 MFMA input projections: Xi = A @ Wi^T + b  (bf16 out, [M][2048])
// ---------------------------------------------------------------------------
__global__ __launch_bounds__(512) void proj_mfma_kernel(
    const ushort* __restrict__ A_we, const ushort* __restrict__ weWi,
    const float* __restrict__ we_b, ushort* __restrict__ XiW,
    const ushort* __restrict__ A_wd, const ushort* __restrict__ wdWi,
    const float* __restrict__ wd_b, ushort* __restrict__ XiD)
{
  int bid = blockIdx.x;
  const ushort* A; const ushort* W; const float* bias; ushort* C; int M, mt, nt;
  if (bid < 1200) { A = A_we; W = weWi; bias = we_b; C = XiW; M = 9600; mt = bid >> 3; nt = bid & 7; }
  else { int b2 = bid - 1200; A = A_wd; W = wdWi; bias = wd_b; C = XiD; M = MROWS; mt = b2 >> 3; nt = b2 & 7; }
  const int tid = threadIdx.x, wid = tid >> 6, lane = tid & 63;
  const int wm = wid >> 2, wn = wid & 3;
  const int m0 = mt * 64 + wm * 32, n0 = nt * 256 + wn * 64;
  const int lr = lane & 15, lk = (lane >> 4) << 3;

  f32x4 acc[2][4];
#pragma unroll
  for (int i = 0; i < 2; ++i)
#pragma unroll
    for (int nf = 0; nf < 4; ++nf) acc[i][nf] = (f32x4)0.0f;

  for (int k0 = 0; k0 < H; k0 += 32) {
    bf16x8 a[2], b[4];
#pragma unroll
    for (int i = 0; i < 2; ++i) {
      int m = m0 + i * 16 + lr;
      bf16x8 az = (bf16x8)(short)0;
      if (m < M) az = *reinterpret_cast<const bf16x8*>(A + (size_t)m * H + k0 + lk);
      a[i] = az;
    }
#pragma unroll
    for (int nf = 0; nf < 4; ++nf)
      b[nf] = *reinterpret_cast<const bf16x8*>(W + (size_t)(n0 + nf * 16 + lr) * H + k0 + lk);
#pragma unroll
    for (int i = 0; i < 2; ++i)
#pragma unroll
      for (int nf = 0; nf < 4; ++nf)
        acc[i][nf] = __builtin_amdgcn_mfma_f32_16x16x32_bf16(a[i], b[nf], acc[i][nf], 0, 0, 0);
  }
#pragma unroll
  for (int i = 0; i < 2; ++i)
#pragma unroll
    for (int nf = 0; nf < 4; ++nf) {
      int n = n0 + nf * 16 + lr;
      float bv = bias[n];
#pragma unroll
      for (int jreg = 0; jreg < 4; ++jreg) {
        int row = m0 + i * 16 + (lane >> 4) * 4 + jreg;
        if (row < M) C[(size_t)row * 2048 + n] = f2b_rne(acc[i][nf][jreg] + bv);
      }
    }
}

// ---------------------------------------------------------------------------
// MEGA: blocks 0..15 = one batch element each, full sequential chain with
// ONLY __syncthreads() (all state in LDS/regs). blocks 16..247 = vocab.
// ---------------------------------------------------------------------------
union SmemU {
  struct {                       // word-encoder phase
    ushort h[32 * 520];          // 33,280 B (rows 20..31 zero)
    float  c[20 * 512];          // 40,960 B
  } we;
  struct {                       // sent-enc + decoder phases
    float  sf[20 * 512];         // 40,960
    ushort so[20 * 520];         // 20,800 (padded rows)
    ushort senc_h[512];
    ushort h[512];
    ushort final_h[512];
    ushort sdh[512];
    ushort cat[1024];
    float  qb[512];
    float  e[20];
    float  align[20];
    float  cov[20];
  } de;
  struct { float red[4][64][2]; } vo;
};

struct MP {
  const ushort* XiW; const ushort* XiD;
  const ushort* weWh; const ushort* seWi; const ushort* seWh;
  const ushort* wfeat; const ushort* wdWh; const ushort* sdWi;
  const ushort* sdWh; const ushort* attnWh; const ushort* Wout;
  const float* se_b; const float* b_feat; const float* sd_b; const float* b_out;
  const float* attn_wc; const float* attn_v; const int* articles;
  float* XiS;                    // [320][2048] f32 (per-b rows s*16+b)
  ushort* wh_bf;                 // [MPAD][512]
  float* loss;
  uint* prog;                    // [16] spaced x16: per-b progress
  uint* vbflags;                 // vocab barrier flags
  const float* Wv; ushort* Wv_bf; const float* bv; float* partials;
};

// M=1 4-gate matmul: acc[g][nf] += h(bcast,LDS) @ W[2048x512]
__device__ __forceinline__ void mm1g(const ushort* hsrc, const ushort* W,
                                     int w, int lr, int lk, f32x4 acc[4][4])
{
#pragma unroll 4
  for (int kt = 0; kt < 16; ++kt) {
    int k0 = kt * 32;
    bf16x8 a = *reinterpret_cast<const bf16x8*>(hsrc + k0 + lk);
#pragma unroll
    for (int g = 0; g < 4; ++g)
#pragma unroll
      for (int nf = 0; nf < 4; ++nf) {
        int col = g * 512 + w * 64 + nf * 16 + lr;
        bf16x8 b = *reinterpret_cast<const bf16x8*>(W + (size_t)col * H + k0 + lk);
        acc[g][nf] = __builtin_amdgcn_mfma_f32_16x16x32_bf16(a, b, acc[g][nf], 0, 0, 0);
      }
  }
}

// M=1 plain matmul (512 cols): acc4[nf] += h(bcast) @ W[512][K]
__device__ __forceinline__ void mm1p(const ushort* hsrc, const ushort* W, int K,
                                     int w, int lr, int lk, f32x4 acc4[4])
{
  for (int k0 = 0; k0 < K; k0 += 32) {
    bf16x8 a = *reinterpret_cast<const bf16x8*>(hsrc + k0 + lk);
#pragma unroll
    for (int nf = 0; nf < 4; ++nf) {
      int col = w * 64 + nf * 16 + lr;
      bf16x8 b = *reinterpret_cast<const bf16x8*>(W + (size_t)col * K + k0 + lk);
      acc4[nf] = __builtin_amdgcn_mfma_f32_16x16x32_bf16(a, b, acc4[nf], 0, 0, 0);
    }
  }
}

__global__ __launch_bounds__(512) void mega_kernel(MP P)
{
  __shared__ SmemU sm;
  const int tid = threadIdx.x, bid = blockIdx.x;
  const int w = tid >> 6, lane = tid & 63;
  const int lr = lane & 15;
  const int lk = (lane >> 4) << 3;
  const bool row0 = (lane >> 4) == 0;   // C row 0 owner (reg 0)

  if (bid >= UBLK) {
    // ======================= VOCAB ROLE =======================
    const int v = bid - UBLK;
    const int mt = v >> 3, chunk = v & 7;

    // wait all b: wenc done (XiW dead) -> convert W_vocab into its space
    if (tid == 0) {
      for (int b = 0; b < UBLK; ++b)
        while (ald_u32(&P.prog[b * 16]) < 1u) __builtin_amdgcn_s_sleep(16);
    }
    __syncthreads();
    {
      const int n4 = VT * H / 4;
      for (int i = v * 512 + tid; i < n4; i += NV * 512) {
        float4 x = reinterpret_cast<const float4*>(P.Wv)[i];
        ushort4 o;
        o.x = f2b_rne(x.x); o.y = f2b_rne(x.y);
        o.z = f2b_rne(x.z); o.w = f2b_rne(x.w);
        reinterpret_cast<ushort4*>(P.Wv_bf)[i] = o;
      }
    }
    sbar(P.vbflags, v, NV, 1u);

    // wait for all b past the sentence covering this row tile
    {
      int lastStep = mt * 4 + 3; if (lastStep > NSTEPS - 1) lastStep = NSTEPS - 1;
      uint want = 2u + (uint)(lastStep / (TT - 1));
      if (tid == 0) {
        for (int b = 0; b < UBLK; ++b)
          while (ald_u32(&P.prog[b * 16]) < want) __builtin_amdgcn_s_sleep(16);
        __builtin_amdgcn_fence(__ATOMIC_ACQUIRE, "agent");
      }
      __syncthreads();
    }

    const int wm = w >> 2, wn = w & 3;
    const int m0 = mt * 64 + wm * 32;
    bf16x8 areg[2][16];
#pragma unroll
    for (int i = 0; i < 2; ++i)
#pragma unroll
      for (int kk = 0; kk < 16; ++kk)
        areg[i][kk] = *reinterpret_cast<const bf16x8*>(
            P.wh_bf + (size_t)(m0 + i * 16 + lr) * H + kk * 32 + lk);

    for (int nt2 = 0; nt2 < 15; ++nt2) {
      const int n0 = chunk * 3840 + nt2 * 256 + wn * 64;
      f32x4 acc[2][4];
#pragma unroll
      for (int i = 0; i < 2; ++i)
#pragma unroll
        for (int nf = 0; nf < 4; ++nf) acc[i][nf] = (f32x4)0.0f;
#pragma unroll 4
      for (int kk = 0; kk < 16; ++kk) {
        bf16x8 b[4];
#pragma unroll
        for (int nf = 0; nf < 4; ++nf) {
          int n = n0 + nf * 16 + lr;
          bf16x8 bz = (bf16x8)(short)0;
          if (n < VT) bz = *reinterpret_cast<const bf16x8*>(P.Wv_bf + (size_t)n * H + kk * 32 + lk);
          b[nf] = bz;
        }
#pragma unroll
        for (int i = 0; i < 2; ++i)
#pragma unroll
          for (int nf = 0; nf < 4; ++nf)
            acc[i][nf] = __builtin_amdgcn_mfma_f32_16x16x32_bf16(areg[i][kk], b[nf], acc[i][nf], 0, 0, 0);
      }
      float bc[4]; int val[4];
#pragma unroll
      for (int nf = 0; nf < 4; ++nf) {
        int n = n0 + nf * 16 + lr;
        val[nf] = (n < VT);
        bc[nf] = val[nf] ? P.bv[n] : 0.f;
      }
#pragma unroll
      for (int i = 0; i < 2; ++i) {
#pragma unroll
        for (int jreg = 0; jreg < 4; ++jreg) {
          float lg[4], mx = -3.0e38f;
#pragma unroll
          for (int nf = 0; nf < 4; ++nf) {
            lg[nf] = val[nf] ? (acc[i][nf][jreg] + bc[nf]) : -3.0e38f;
            mx = fmaxf(mx, lg[nf]);
          }
#pragma unroll
          for (int d = 1; d < 16; d <<= 1) mx = fmaxf(mx, __shfl_xor(mx, d));
          float s = 0.f;
#pragma unroll
          for (int nf = 0; nf < 4; ++nf) s += val[nf] ? expf(lg[nf] - mx) : 0.f;
#pragma unroll
          for (int d = 1; d < 16; d <<= 1) s += __shfl_xor(s, d);
          if (lr == 0) {
            int rloc = wm * 32 + i * 16 + (lane >> 4) * 4 + jreg;
            sm.vo.red[wn][rloc][0] = mx;
            sm.vo.red[wn][rloc][1] = s;
          }
        }
      }
      __syncthreads();
      if (tid < 64) {
        float M = -3.0e38f;
#pragma unroll
        for (int q = 0; q < 4; ++q) M = fmaxf(M, sm.vo.red[q][tid][0]);
        float S = 0.f;
#pragma unroll
        for (int q = 0; q < 4; ++q) S += sm.vo.red[q][tid][1] * expf(sm.vo.red[q][tid][0] - M);
        size_t p = ((size_t)(mt * 64 + tid) * NT2 + chunk * 15 + nt2) * 2;
        P.partials[p] = M;
        P.partials[p + 1] = S;
      }
      __syncthreads();
    }
    return;
  }

  // ======================= SEQUENTIAL ROLE (b = bid) =======================
  const int b_ = bid;

  // ---- Phase 1: word encoder, M=20 (2 mtiles), 30 steps ----
  {
    for (int i = tid; i < 32 * 520; i += 512) sm.we.h[i] = 0;
    for (int i = tid; i < 20 * 512; i += 512) sm.we.c[i] = 0.f;
    __syncthreads();

    for (int l = 0; l < LL; ++l) {
      f32x4 acc[4][2][4];
#pragma unroll
      for (int g = 0; g < 4; ++g)
#pragma unroll
        for (int mt = 0; mt < 2; ++mt)
#pragma unroll
          for (int nf = 0; nf < 4; ++nf) acc[g][mt][nf] = (f32x4)0.0f;
#pragma unroll 2
      for (int kt = 0; kt < 16; ++kt) {
        int k0 = kt * 32;
        bf16x8 a[2];
#pragma unroll
        for (int mt = 0; mt < 2; ++mt)
          a[mt] = *reinterpret_cast<const bf16x8*>(&sm.we.h[(mt * 16 + lr) * 520 + k0 + lk]);
#pragma unroll
        for (int g = 0; g < 4; ++g)
#pragma unroll
          for (int nf = 0; nf < 4; ++nf) {
            int col = g * 512 + w * 64 + nf * 16 + lr;
            bf16x8 bb = *reinterpret_cast<const bf16x8*>(P.weWh + (size_t)col * H + k0 + lk);
#pragma unroll
            for (int mt = 0; mt < 2; ++mt)
              acc[g][mt][nf] = __builtin_amdgcn_mfma_f32_16x16x32_bf16(a[mt], bb, acc[g][mt][nf], 0, 0, 0);
          }
      }
      __syncthreads();
#pragma unroll
      for (int mt = 0; mt < 2; ++mt)
#pragma unroll
        for (int reg = 0; reg < 4; ++reg) {
          int s = mt * 16 + (lane >> 4) * 4 + reg;
          if (s < SS) {
#pragma unroll
            for (int nf = 0; nf < 4; ++nf) {
              int u = w * 64 + nf * 16 + lr;
              const ushort* xi = P.XiW + (size_t)(l * 320 + s * 16 + b_) * 2048 + u;
              float gi = acc[0][mt][nf][reg] + b2f(xi[0]);
              float gf = acc[1][mt][nf][reg] + b2f(xi[512]);
              float gc = acc[2][mt][nf][reg] + b2f(xi[1024]);
              float go = acc[3][mt][nf][reg] + b2f(xi[1536]);
              float c = sigmoidf_(gf) * sm.we.c[s * 512 + u] + sigmoidf_(gi) * tanhf(gc);
              float h = sigmoidf_(go) * tanhf(c);
              sm.we.c[s * 512 + u] = c;
              sm.we.h[s * 520 + u] = f2b_rne(h);
            }
          }
        }
      __syncthreads();
    }

    // XiS = h30 @ se_Wi^T + se_b  (f32, global, rows s*16+b)
    {
      f32x4 acc[4][2][4];
#pragma unroll
      for (int g = 0; g < 4; ++g)
#pragma unroll
        for (int mt = 0; mt < 2; ++mt)
#pragma unroll
          for (int nf = 0; nf < 4; ++nf) acc[g][mt][nf] = (f32x4)0.0f;
#pragma unroll 2
      for (int kt = 0; kt < 16; ++kt) {
        int k0 = kt * 32;
        bf16x8 a[2];
#pragma unroll
        for (int mt = 0; mt < 2; ++mt)
          a[mt] = *reinterpret_cast<const bf16x8*>(&sm.we.h[(mt * 16 + lr) * 520 + k0 + lk]);
#pragma unroll
        for (int g = 0; g < 4; ++g)
#pragma unroll
          for (int nf = 0; nf < 4; ++nf) {
            int col = g * 512 + w * 64 + nf * 16 + lr;
            bf16x8 bb = *reinterpret_cast<const bf16x8*>(P.seWi + (size_t)col * H + k0 + lk);
#pragma unroll
            for (int mt = 0; mt < 2; ++mt)
              acc[g][mt][nf] = __builtin_amdgcn_mfma_f32_16x16x32_bf16(a[mt], bb, acc[g][mt][nf], 0, 0, 0);
          }
      }
#pragma unroll
      for (int mt = 0; mt < 2; ++mt)
#pragma unroll
        for (int reg = 0; reg < 4; ++reg) {
          int s = mt * 16 + (lane >> 4) * 4 + reg;
          if (s < SS) {
#pragma unroll
            for (int nf = 0; nf < 4; ++nf) {
              int u = w * 64 + nf * 16 + lr;
#pragma unroll
              for (int g = 0; g < 4; ++g)
                P.XiS[(size_t)(s * 16 + b_) * 2048 + g * 512 + u] =
                    acc[g][mt][nf][reg] + P.se_b[g * 512 + u];
            }
          }
        }
    }
    __syncthreads();
    if (tid == 0) {
      __builtin_amdgcn_fence(__ATOMIC_RELEASE, "agent");
      ast_u32(&P.prog[b_ * 16], 1u);    // XiW-b dead
    }
  }

  // ---- Phase 2: sentence encoder, M=1, 20 steps ----
  float cse[4] = {0.f, 0.f, 0.f, 0.f};
  {
    for (int i = tid; i < 512; i += 512) sm.de.senc_h[i] = 0;
    __syncthreads();
    for (int s = 0; s < SS; ++s) {
      f32x4 acc[4][4];
#pragma unroll
      for (int g = 0; g < 4; ++g)
#pragma unroll
        for (int nf = 0; nf < 4; ++nf) acc[g][nf] = (f32x4)0.0f;
      mm1g(sm.de.senc_h, P.seWh, w, lr, lk, acc);
      __syncthreads();
      if (row0) {
#pragma unroll
        for (int nf = 0; nf < 4; ++nf) {
          int u = w * 64 + nf * 16 + lr;
          const float* xi = P.XiS + (size_t)(s * 16 + b_) * 2048 + u;
          float gi = acc[0][nf][0] + xi[0];
          float gf = acc[1][nf][0] + xi[512];
          float gc = acc[2][nf][0] + xi[1024];
          float go = acc[3][nf][0] + xi[1536];
          float c = sigmoidf_(gf) * cse[nf] + sigmoidf_(gi) * tanhf(gc);
          float h = sigmoidf_(go) * tanhf(c);
          cse[nf] = c;
          ushort hb = f2b_rne(h);
          sm.de.senc_h[u] = hb;
          sm.de.so[s * 520 + u] = hb;
        }
      }
      __syncthreads();
    }
  }

  // ---- sent_feat = sent_out @ W_feat^T + b_feat (M=20) ----
  {
    f32x4 acc2[2][4];
#pragma unroll
    for (int mt = 0; mt < 2; ++mt)
#pragma unroll
      for (int nf = 0; nf < 4; ++nf) acc2[mt][nf] = (f32x4)0.0f;
#pragma unroll 2
    for (int kt = 0; kt < 16; ++kt) {
      int k0 = kt * 32;
      bf16x8 a[2];
#pragma unroll
      for (int mt = 0; mt < 2; ++mt)
        a[mt] = *reinterpret_cast<const bf16x8*>(&sm.de.so[(mt * 16 + lr) * 520 + k0 + lk]);
#pragma unroll
      for (int nf = 0; nf < 4; ++nf) {
        int col = w * 64 + nf * 16 + lr;
        bf16x8 bb = *reinterpret_cast<const bf16x8*>(P.wfeat + (size_t)col * H + k0 + lk);
#pragma unroll
        for (int mt = 0; mt < 2; ++mt)
          acc2[mt][nf] = __builtin_amdgcn_mfma_f32_16x16x32_bf16(a[mt], bb, acc2[mt][nf], 0, 0, 0);
      }
    }
    __syncthreads();
#pragma unroll
    for (int mt = 0; mt < 2; ++mt)
#pragma unroll
      for (int reg = 0; reg < 4; ++reg) {
        int s = mt * 16 + (lane >> 4) * 4 + reg;
        if (s < SS) {
#pragma unroll
          for (int nf = 0; nf < 4; ++nf) {
            int u = w * 64 + nf * 16 + lr;
            sm.de.sf[s * 512 + u] = acc2[mt][nf][reg] + P.b_feat[u];
          }
        }
      }
    // coverage init
    if (tid < SS) sm.de.cov[tid] = 0.f;
    __syncthreads();
  }

  // ---- hierarchical decoder (all per-b, LDS-local) ----
  float cw[4], csd[4];
#pragma unroll
  for (int nf = 0; nf < 4; ++nf) { cw[nf] = cse[nf]; csd[nf] = cse[nf]; }

  for (int n = 0; n < NN; ++n) {
    // h := (n==0) ? senc_h : final_h
    {
      const ushort* src = (n == 0) ? sm.de.senc_h : sm.de.final_h;
      if (tid < 512) sm.de.h[tid] = src[tid];
      __syncthreads();
    }
    // 19 word-decoder steps
    for (int t = 0; t < TT - 1; ++t) {
      int stp = n * (TT - 1) + t;
      f32x4 acc[4][4];
#pragma unroll
      for (int g = 0; g < 4; ++g)
#pragma unroll
        for (int nf = 0; nf < 4; ++nf) acc[g][nf] = (f32x4)0.0f;
      mm1g(sm.de.h, P.wdWh, w, lr, lk, acc);
      __syncthreads();
      if (row0) {
#pragma unroll
        for (int nf = 0; nf < 4; ++nf) {
          int u = w * 64 + nf * 16 + lr;
          const ushort* xi = P.XiD + (size_t)(stp * 16 + b_) * 2048 + u;
          float gi = acc[0][nf][0] + b2f(xi[0]);
          float gf = acc[1][nf][0] + b2f(xi[512]);
          float gc = acc[2][nf][0] + b2f(xi[1024]);
          float go = acc[3][nf][0] + b2f(xi[1536]);
          float c = sigmoidf_(gf) * cw[nf] + sigmoidf_(gi) * tanhf(gc);
          float h = sigmoidf_(go) * tanhf(c);
          cw[nf] = c;
          ushort hb = f2b_rne(h);
          sm.de.h[u] = hb;
          P.wh_bf[(size_t)(stp * 16 + b_) * H + u] = hb;
        }
      }
      __syncthreads();
    }
    // publish: sentence n wh rows for this b are visible
    if (tid == 0) {
      __builtin_amdgcn_fence(__ATOMIC_RELEASE, "agent");
      ast_u32(&P.prog[b_ * 16], 2u + (uint)n);
    }
    // sentence-decoder LSTM step: x = w_hx (sdWi), h = s_hx (sdWh)
    {
      f32x4 acc[4][4];
#pragma unroll
      for (int g = 0; g < 4; ++g)
#pragma unroll
        for (int nf = 0; nf < 4; ++nf) acc[g][nf] = (f32x4)0.0f;
      mm1g(sm.de.h, P.sdWi, w, lr, lk, acc);
      mm1g((n == 0) ? sm.de.senc_h : sm.de.final_h, P.sdWh, w, lr, lk, acc);
      __syncthreads();
      if (row0) {
#pragma unroll
        for (int nf = 0; nf < 4; ++nf) {
          int u = w * 64 + nf * 16 + lr;
          float gi = acc[0][nf][0] + P.sd_b[0 * 512 + u];
          float gf = acc[1][nf][0] + P.sd_b[1 * 512 + u];
          float gc = acc[2][nf][0] + P.sd_b[2 * 512 + u];
          float go = acc[3][nf][0] + P.sd_b[3 * 512 + u];
          float c = sigmoidf_(gf) * csd[nf] + sigmoidf_(gi) * tanhf(gc);
          float h = sigmoidf_(go) * tanhf(c);
          csd[nf] = c;
          sm.de.sdh[u] = f2b_rne(h);
        }
      }
      __syncthreads();
    }
    // qb = sdh @ attn_Wh^T
    {
      f32x4 a4[4];
#pragma unroll
      for (int nf = 0; nf < 4; ++nf) a4[nf] = (f32x4)0.0f;
      mm1p(sm.de.sdh, P.attnWh, H, w, lr, lk, a4);
      __syncthreads();
      if (row0) {
#pragma unroll
        for (int nf = 0; nf < 4; ++nf)
          sm.de.qb[w * 64 + nf * 16 + lr] = a4[nf][0];
      }
      __syncthreads();
    }
    // e[s]
    for (int s = w; s < SS; s += 8) {
      float cov = sm.de.cov[s];
      float sum = 0.f;
      for (int h2 = lane; h2 < H; h2 += 64)
        sum += tanhf(sm.de.sf[s * 512 + h2] + sm.de.qb[h2] +
                     cov * P.attn_wc[h2]) * P.attn_v[h2];
#pragma unroll
      for (int d = 1; d < 64; d <<= 1) sum += __shfl_xor(sum, d);
      if (lane == 0)
        sm.de.e[s] = (P.articles[(s * 16 + b_) * LL] > 0) ? sum : -1e9f;
    }
    __syncthreads();
    // softmax over s + coverage loss + coverage update (wave 0)
    if (w == 0) {
      float ev = (lane < SS) ? sm.de.e[lane] : -3.0e38f;
      float mx = ev;
#pragma unroll
      for (int d = 1; d < 64; d <<= 1) mx = fmaxf(mx, __shfl_xor(mx, d));
      float ex = (lane < SS) ? expf(ev - mx) : 0.f;
      float s = ex;
#pragma unroll
      for (int d = 1; d < 64; d <<= 1) s += __shfl_xor(s, d);
      float al = ex / s;
      float cl = 0.f;
      if (lane < SS) {
        float cov = sm.de.cov[lane];
        cl = fminf(al, cov);
        sm.de.cov[lane] = cov + al;
        sm.de.align[lane] = al;
      }
#pragma unroll
      for (int d = 1; d < 64; d <<= 1) cl += __shfl_xor(cl, d);
      if (lane == 0) atomicAdd(P.loss, cl * (1.f / BB));
    }
    __syncthreads();
    // context + cat = [ctx | sdh]
    if (tid < 512) {
      float s = 0.f;
#pragma unroll
      for (int ss2 = 0; ss2 < SS; ++ss2)
        s += sm.de.align[ss2] * b2f(sm.de.so[ss2 * 520 + tid]);
      sm.de.cat[tid] = f2b_rne(s);
      sm.de.cat[512 + tid] = sm.de.sdh[tid];
    }
    __syncthreads();
    // final = tanh(cat @ W_out^T + b_out)
    {
      f32x4 a4[4];
#pragma unroll
      for (int nf = 0; nf < 4; ++nf) a4[nf] = (f32x4)0.0f;
      mm1p(sm.de.cat, P.Wout, 2 * H, w, lr, lk, a4);
      __syncthreads();
      if (row0) {
#pragma unroll
        for (int nf = 0; nf < 4; ++nf) {
          int u = w * 64 + nf * 16 + lr;
          sm.de.final_h[u] = f2b_rne(tanhf(a4[nf][0] + P.b_out[u]));
        }
      }
      __syncthreads();
    }
  }
}

// target logit per decoder row (consistent bf16 operands)
__global__ void tlog_kernel(const ushort* __restrict__ wh_bf,
                            const ushort* __restrict__ Wv_bf,
                            const float* __restrict__ bv,
                            const int* __restrict__ summaries,
                            float* __restrict__ tlog)
{
  int row = blockIdx.x;
  int lane = threadIdx.x;
  int b = row & 15, stp = row >> 4;
  int n = stp / (TT - 1), t = stp % (TT - 1);
  int tgt = summaries[(n * BB + b) * TT + t + 1];
  float s = 0.f;
  for (int k = lane; k < H; k += 64)
    s += b2f(wh_bf[(size_t)row * H + k]) * b2f(Wv_bf[(size_t)tgt * H + k]);
#pragma unroll
  for (int d = 1; d < 64; d <<= 1) s += __shfl_xor(s, d);
  if (lane == 0) tlog[row] = s + bv[tgt];
}

// per-step masked-mean NLL from partials
__global__ __launch_bounds__(256) void nll_kernel(
    const float* __restrict__ partials, const float* __restrict__ tlog,
    const int* __restrict__ summaries, float* __restrict__ loss)
{
  int stp = blockIdx.x;
  int tid = threadIdx.x;
  int rr = tid >> 4, ch = tid & 15;
  int row = stp * 16 + rr;
  const float* pr = partials + (size_t)row * NT2 * 2;
  float mx = -3.0e38f;
  for (int t2 = ch; t2 < NT2; t2 += 16) mx = fmaxf(mx, pr[t2 * 2]);
#pragma unroll
  for (int d = 1; d < 16; d <<= 1) mx = fmaxf(mx, __shfl_xor(mx, d));
  float s = 0.f;
  for (int t2 = ch; t2 < NT2; t2 += 16) s += pr[t2 * 2 + 1] * expf(pr[t2 * 2] - mx);
#pragma unroll
  for (int d = 1; d < 16; d <<= 1) s += __shfl_xor(s, d);
  __shared__ float sh_n[16], sh_m[16];
  if (ch == 0) {
    float lse = mx + logf(s);
    float nll = lse - tlog[row];
    int b = row & 15;
    int n = stp / (TT - 1), t = stp % (TT - 1);
    int wa = summaries[(n * BB + b) * TT + t + 1];
    sh_n[rr] = (wa != 0) ? nll : 0.f;
    sh_m[rr] = (wa != 0) ? 1.f : 0.f;
  }
  __syncthreads();
  if (tid == 0) {
    float sn = 0.f, smm = 0.f;
    for (int r2 = 0; r2 < 16; ++r2) { sn += sh_n[r2]; smm += sh_m[r2]; }
    atomicAdd(loss, sn / fmaxf(smm, 1.f));
  }
}

// ---------------------------------------------------------------------------
extern "C" void kernel_launch(void* const* d_in, const int* in_sizes, int n_in,
                              void* d_out, int out_size, void* d_ws, size_t ws_size,
                              hipStream_t stream)
{
  (void)in_sizes; (void)n_in; (void)out_size; (void)ws_size;
  const int*   articles  = (const int*)d_in[0];
  const int*   summaries = (const int*)d_in[1];
  const float* emb_src   = (const float*)d_in[2];
  const float* emb_tgt   = (const float*)d_in[3];
  const float* we_Wi = (const float*)d_in[4];
  const float* we_Wh = (const float*)d_in[5];
  const float* we_b  = (const float*)d_in[6];
  const float* se_Wi = (const float*)d_in[7];
  const float* se_Wh = (const float*)d_in[8];
  const float* se_b  = (const float*)d_in[9];
  const float* W_feat = (const float*)d_in[10];
  const float* b_feat = (const float*)d_in[11];
  const float* wd_Wi = (const float*)d_in[12];
  const float* wd_Wh = (const float*)d_in[13];
  const float* wd_b  = (const float*)d_in[14];
  const float* W_vocab = (const float*)d_in[15];
  const float* b_vocab = (const float*)d_in[16];
  const float* sd_Wi = (const float*)d_in[17];
  const float* sd_Wh = (const float*)d_in[18];
  const float* sd_b  = (const float*)d_in[19];
  const float* attn_Wh = (const float*)d_in[20];
  const float* attn_wc = (const float*)d_in[21];
  const float* attn_v  = (const float*)d_in[22];
  const float* W_out = (const float*)d_in[23];
  const float* b_out = (const float*)d_in[24];

  char* wsb = (char*)d_ws;
  size_t off = 0;
  auto alloc = [&](size_t bytes) -> char* {
    char* p = wsb + off;
    off += (bytes + 255) & ~(size_t)255;
    return p;
  };

  // regA: A_we (prep->proj) UNION {wh_bf, partials, tlog} (mega onwards)
  char* regA = alloc(9830400);
  ushort* A_we     = (ushort*)regA;
  ushort* wh_bf    = (ushort*)regA;                    // 1856*512*2
  float*  partials = (float*)(regA + 1900544);         // 1856*120*2*4
  float*  tlogb    = (float*)(regA + 3682304);         // 1824*4

  ushort* A_wd = (ushort*)alloc((size_t)MROWS * H * 2);

  // regW: XiW bf16 (proj->mega word-enc) UNION Wv_bf (vocab role)
  char* regW = alloc((size_t)9600 * 2048 * 2);
  ushort* XiW   = (ushort*)regW;
  ushort* Wv_bf = (ushort*)regW;

  ushort* XiD = (ushort*)alloc((size_t)MROWS * 2048 * 2);

  ushort* weWi  = (ushort*)alloc(4 * H * H * 2);
  ushort* wdWi  = (ushort*)alloc(4 * H * H * 2);
  ushort* weWh  = (ushort*)alloc(4 * H * H * 2);
  ushort* seWi  = (ushort*)alloc(4 * H * H * 2);
  ushort* seWh  = (ushort*)alloc(4 * H * H * 2);
  ushort* wdWh  = (ushort*)alloc(4 * H * H * 2);
  ushort* sdWi  = (ushort*)alloc(4 * H * H * 2);
  ushort* sdWh  = (ushort*)alloc(4 * H * H * 2);
  ushort* wfeat = (ushort*)alloc(H * H * 2);
  ushort* attnWh= (ushort*)alloc(H * H * 2);
  ushort* Wout  = (ushort*)alloc(H * 2 * H * 2);

  float*  XiS     = (float*)alloc((size_t)320 * 2048 * 4);
  uint*   prog    = (uint*)alloc(UBLK * 16 * 4);
  uint*   vbflags = (uint*)alloc(NV * 16 * 4);

  float* loss = (float*)d_out;
  hipMemsetAsync(loss, 0, 4, stream);
  hipMemsetAsync(prog, 0, UBLK * 16 * 4, stream);
  hipMemsetAsync(vbflags, 0, NV * 16 * 4, stream);

  // 1) prep
  {
    PrepP P = {articles, summaries, emb_src, emb_tgt,
               we_Wi, wd_Wi, we_Wh, se_Wi, se_Wh, W_feat,
               wd_Wh, sd_Wi, sd_Wh, attn_Wh, W_out,
               A_we, A_wd, weWi, wdWi, weWh, seWi, seWh, wfeat,
               wdWh, sdWi, sdWh, attnWh, Wout};
    prep_kernel<<<2048, 256, 0, stream>>>(P);
  }

  // 2) input projections
  proj_mfma_kernel<<<1432, 512, 0, stream>>>(A_we, weWi, we_b, XiW,
                                             A_wd, wdWi, wd_b, XiD);

  // zero wh_bf pad rows (A_we dead after proj; stream-ordered)
  hipMemsetAsync((char*)wh_bf + (size_t)MROWS * H * 2, 0,
                 (size_t)(MPAD - MROWS) * H * 2, stream);

  // 3) MEGA: 16 per-batch sequential blocks + 232 vocab blocks
  {
    MP P;
    P.XiW = XiW; P.XiD = XiD;
    P.weWh = weWh; P.seWi = seWi; P.seWh = seWh; P.wfeat = wfeat;
    P.wdWh = wdWh; P.sdWi = sdWi; P.sdWh = sdWh; P.attnWh = attnWh; P.Wout = Wout;
    P.se_b = se_b; P.b_feat = b_feat; P.sd_b = sd_b; P.b_out = b_out;
    P.attn_wc = attn_wc; P.attn_v = attn_v; P.articles = articles;
    P.XiS = XiS; P.wh_bf = wh_bf; P.loss = loss;
    P.prog = prog; P.vbflags = vbflags;
    P.Wv = W_vocab; P.Wv_bf = Wv_bf; P.bv = b_vocab; P.partials = partials;
    mega_kernel<<<MEGA, 512, 0, stream>>>(P);
  }

  // 4) target logits + NLL
  tlog_kernel<<<MROWS, 64, 0, stream>>>(wh_bf, Wv_bf, b_vocab, summaries, tlogb);
  nll_kernel<<<NSTEPS, 256, 0, stream>>>(partials, tlogb, summaries, loss);
}

// Round 10
// 5070.047 us; speedup vs baseline: 2.2573x; 2.2573x over previous
//
#include <hip/hip_runtime.h>
#include <cstdint>
#include <cstddef>

#define H 512
#define SS 20
#define BB 16
#define LL 30
#define NN 6
#define TT 20
#define VT 30000
#define MROWS 1824   /* N*B*(T-1) */
#define NSTEPS 114   /* N*(T-1) */
#define MPAD 1856    /* 29*64 */
#define NT2 120      /* 8 chunks * 15 tiles of 256 */
#define UBLK 16      /* sequential-role blocks */
#define NV 232       /* vocab-role blocks = 29 mt * 8 chunks */
#define MEGA 248

#define SCOPE_AGENT __HIP_MEMORY_SCOPE_AGENT

typedef __attribute__((ext_vector_type(8))) short bf16x8;
typedef __attribute__((ext_vector_type(4))) float f32x4;

__device__ __forceinline__ float sigmoidf_(float x) { return 1.f / (1.f + expf(-x)); }
__device__ __forceinline__ float b2f(ushort u) { return __uint_as_float(((uint32_t)u) << 16); }
__device__ __forceinline__ ushort f2b_rne(float f) {
  uint32_t u = __float_as_uint(f);
  return (ushort)((u + 0x7fffu + ((u >> 16) & 1u)) >> 16);
}

__device__ __forceinline__ void ast_u32(uint* p, uint v) {
  __hip_atomic_store(p, v, __ATOMIC_RELAXED, SCOPE_AGENT);
}
__device__ __forceinline__ uint ald_u32(const uint* p) {
  return __hip_atomic_load(p, __ATOMIC_RELAXED, SCOPE_AGENT);
}

// ---------------------------------------------------------------------------
// heater wait, divergence-safe: ALL 64 lanes of wave 0 poll the global flag
// (same address -> one broadcast transaction, uniform wave-wide exit); lane 0
// then sets an LDS flag; waves 1..7 spin on the LDS flag (inter-wave, safe).
// FMA chains between polls keep the CU's VALU busy (hold gfxclk at boost).
// NO intra-wave producer->consumer spin (R9's deadlock).
// ---------------------------------------------------------------------------
__device__ __forceinline__ void heat_wait(const uint* p, uint want,
                                          volatile uint* lflag, int tid)
{
  if (tid == 0) *lflag = 0u;
  __syncthreads();
  float x = 1.f;
  const float y = 1.0000001f;
  if (tid < 64) {                        // whole wave 0, no divergence
    while (ald_u32(p) < want) {
#pragma unroll 16
      for (int i = 0; i < 512; ++i) x = __builtin_fmaf(x, y, 1e-7f);
      if (x > 1e30f) x = 1.f;
    }
    if (tid == 0) *lflag = 1u;
  } else {                               // waves 1..7: spin on LDS flag
    while (*lflag == 0u) {
#pragma unroll 16
      for (int i = 0; i < 512; ++i) x = __builtin_fmaf(x, y, 1e-7f);
      if (x > 1e30f) x = 1.f;
    }
  }
  asm volatile("" :: "v"(x));
  __syncthreads();
}

// ---------------------------------------------------------------------------
// grid barrier, fence-minimal (R7-validated)
// ---------------------------------------------------------------------------
__device__ __forceinline__ void sbar(uint* flags, int slot, int nblk, uint phase)
{
  __syncthreads();
  if (threadIdx.x == 0) {
    __builtin_amdgcn_fence(__ATOMIC_RELEASE, "agent");   // wb dirty L2 once
    ast_u32(&flags[slot * 16], phase);
  }
  if ((int)threadIdx.x < nblk) {
    while (ald_u32(&flags[threadIdx.x * 16]) < phase)
      __builtin_amdgcn_s_sleep(1);
  }
  __syncthreads();
  if (threadIdx.x == 0)
    __builtin_amdgcn_fence(__ATOMIC_ACQUIRE, "agent");   // inv L1+L2 once
  __syncthreads();
}

// ---------------------------------------------------------------------------
// prep: token gathers -> bf16 A matrices; weight matrices f32 -> bf16
// ---------------------------------------------------------------------------
struct PrepP {
  const int* articles; const int* summaries;
  const float* emb_src; const float* emb_tgt;
  const float* we_Wi; const float* wd_Wi; const float* we_Wh;
  const float* se_Wi; const float* se_Wh; const float* W_feat;
  const float* wd_Wh; const float* sd_Wi; const float* sd_Wh;
  const float* attn_Wh; const float* W_out;
  ushort* A_we; ushort* A_wd;
  ushort* weWi; ushort* wdWi; ushort* weWh;
  ushort* seWi; ushort* seWh; ushort* wfeat;
  ushort* wdWh; ushort* sdWi; ushort* sdWh;
  ushort* attnWh; ushort* Wout;
};

__device__ __forceinline__ void conv_f2b(const float* __restrict__ src,
                                         ushort* __restrict__ dst, int n4,
                                         int t0, int stride)
{
  for (int i = t0; i < n4; i += stride) {
    float4 v = reinterpret_cast<const float4*>(src)[i];
    ushort4 o;
    o.x = f2b_rne(v.x); o.y = f2b_rne(v.y);
    o.z = f2b_rne(v.z); o.w = f2b_rne(v.w);
    reinterpret_cast<ushort4*>(dst)[i] = o;
  }
}

__global__ __launch_bounds__(256) void prep_kernel(PrepP P)
{
  const int t0 = blockIdx.x * 256 + threadIdx.x;
  const int stride = gridDim.x * 256;
  for (int i = t0; i < SS * BB * LL * H; i += stride) {
    int m = i >> 9, k = i & 511;
    int l = m / (SS * BB), sb = m % (SS * BB);
    int tok = P.articles[sb * LL + l];
    P.A_we[i] = f2b_rne(P.emb_src[(size_t)tok * H + k]);
  }
  for (int i = t0; i < MROWS * H; i += stride) {
    int m = i >> 9, k = i & 511;
    int stp = m >> 4, b = m & 15;
    int n = stp / (TT - 1), t = stp % (TT - 1);
    int tok = P.summaries[(n * BB + b) * TT + t];
    P.A_wd[i] = f2b_rne(P.emb_tgt[(size_t)tok * H + k]);
  }
  const int Q = 4 * H * H / 4;
  conv_f2b(P.we_Wi, P.weWi, Q, t0, stride);
  conv_f2b(P.wd_Wi, P.wdWi, Q, t0, stride);
  conv_f2b(P.we_Wh, P.weWh, Q, t0, stride);
  conv_f2b(P.se_Wi, P.seWi, Q, t0, stride);
  conv_f2b(P.se_Wh, P.seWh, Q, t0, stride);
  conv_f2b(P.wd_Wh, P.wdWh, Q, t0, stride);
  conv_f2b(P.sd_Wi, P.sdWi, Q, t0, stride);
  conv_f2b(P.sd_Wh, P.sdWh, Q, t0, stride);
  conv_f2b(P.W_feat, P.wfeat, H * H / 4, t0, stride);
  conv_f2b(P.attn_Wh, P.attnWh, H * H / 4, t0, stride);
  conv_f2b(P.W_out, P.Wout, H * 2 * H / 4, t0, stride);
}

// ---------------------------------------------------------------------------
// bf16 MFMA input projections: Xi = A @ Wi^T + b  (bf16 out, [M][2048])
// ---------------------------------------------------------------------------
__global__ __launch_bounds__(512) void proj_mfma_kernel(
    const ushort* __restrict__ A_we, const ushort* __restrict__ weWi,
    const float* __restrict__ we_b, ushort* __restrict__ XiW,
    const ushort* __restrict__ A_wd, const ushort* __restrict__ wdWi,
    const float* __restrict__ wd_b, ushort* __restrict__ XiD)
{
  int bid = blockIdx.x;
  const ushort* A; const ushort* W; const float* bias; ushort* C; int M, mt, nt;
  if (bid < 1200) { A = A_we; W = weWi; bias = we_b; C = XiW; M = 9600; mt = bid >> 3; nt = bid & 7; }
  else { int b2 = bid - 1200; A = A_wd; W = wdWi; bias = wd_b; C = XiD; M = MROWS; mt = b2 >> 3; nt = b2 & 7; }
  const int tid = threadIdx.x, wid = tid >> 6, lane = tid & 63;
  const int wm = wid >> 2, wn = wid & 3;
  const int m0 = mt * 64 + wm * 32, n0 = nt * 256 + wn * 64;
  const int lr = lane & 15, lk = (lane >> 4) << 3;

  f32x4 acc[2][4];
#pragma unroll
  for (int i = 0; i < 2; ++i)
#pragma unroll
    for (int nf = 0; nf < 4; ++nf) acc[i][nf] = (f32x4)0.0f;

  for (int k0 = 0; k0 < H; k0 += 32) {
    bf16x8 a[2], b[4];
#pragma unroll
    for (int i = 0; i < 2; ++i) {
      int m = m0 + i * 16 + lr;
      bf16x8 az = (bf16x8)(short)0;
      if (m < M) az = *reinterpret_cast<const bf16x8*>(A + (size_t)m * H + k0 + lk);
      a[i] = az;
    }
#pragma unroll
    for (int nf = 0; nf < 4; ++nf)
      b[nf] = *reinterpret_cast<const bf16x8*>(W + (size_t)(n0 + nf * 16 + lr) * H + k0 + lk);
#pragma unroll
    for (int i = 0; i < 2; ++i)
#pragma unroll
      for (int nf = 0; nf < 4; ++nf)
        acc[i][nf] = __builtin_amdgcn_mfma_f32_16x16x32_bf16(a[i], b[nf], acc[i][nf], 0, 0, 0);
  }
#pragma unroll
  for (int i = 0; i < 2; ++i)
#pragma unroll
    for (int nf = 0; nf < 4; ++nf) {
      int n = n0 + nf * 16 + lr;
      float bv = bias[n];
#pragma unroll
      for (int jreg = 0; jreg < 4; ++jreg) {
        int row = m0 + i * 16 + (lane >> 4) * 4 + jreg;
        if (row < M) C[(size_t)row * 2048 + n] = f2b_rne(acc[i][nf][jreg] + bv);
      }
    }
}

// ---------------------------------------------------------------------------
// MEGA kernel: blocks 0..15 = sequential chain; 16..247 = vocab pipeline
// (divergence-safe heater waits hold gfxclk at boost while idle).
// ---------------------------------------------------------------------------
struct MP {
  const ushort* XiW; const ushort* XiD;
  const ushort* weWh; const ushort* seWi; const ushort* seWh;
  const ushort* wfeat; const ushort* wdWh; const ushort* sdWi;
  const ushort* sdWh; const ushort* attnWh; const ushort* Wout;
  const float* se_b; const float* b_feat; const float* sd_b; const float* b_out;
  const float* attn_wc; const float* attn_v; const int* articles;
  ushort* h0; ushort* h1;
  float* XiS;
  ushort* sh0; ushort* sh1;
  float* sent_out; ushort* sent_out_bf; float* sent_feat;
  ushort* wh_bf; ushort* sdh_bf; ushort* final_bf; ushort* catb;
  float* qb; float* ebuf; float* alignb; float* covb; float* loss;
  uint* sflags;       // UBLK barrier flags
  uint* vbflags;      // NV barrier flags
  uint* vflag;        // producer->consumer progress
  const float* Wv; ushort* Wv_bf; const float* bv; float* partials;
};

__global__ __launch_bounds__(512) void mega_kernel(MP P)
{
  __shared__ uint heatflag;
  const int tid = threadIdx.x, bid = blockIdx.x;
  const int wid = tid >> 6, lane = tid & 63;
  const int lr = lane & 15;
  const int lk = (lane >> 4) << 3;
  const int orow = (lane >> 4) << 2;

  if (bid >= UBLK) {
    // ================= VOCAB ROLE =================
    const int v = bid - UBLK;            // 0..231
    const int mt = v >> 3, chunk = v & 7;
    __shared__ float red[4][64][2];

    // heat-wait until XiW is dead, then convert W_vocab
    heat_wait(P.vflag, 1u, &heatflag, tid);
    {
      const int n4 = VT * H / 4;
      for (int i = v * 512 + tid; i < n4; i += NV * 512) {
        float4 w = reinterpret_cast<const float4*>(P.Wv)[i];
        ushort4 o;
        o.x = f2b_rne(w.x); o.y = f2b_rne(w.y);
        o.z = f2b_rne(w.z); o.w = f2b_rne(w.w);
        reinterpret_cast<ushort4*>(P.Wv_bf)[i] = o;
      }
    }
    sbar(P.vbflags, v, NV, 1u);          // all Wv_bf visible to all V blocks

    // heat-wait for the sentence containing this row tile, then fence once
    {
      int lastStep = mt * 4 + 3; if (lastStep > NSTEPS - 1) lastStep = NSTEPS - 1;
      uint want = 2u + (uint)(lastStep / (TT - 1));
      heat_wait(P.vflag, want, &heatflag, tid);
      if (tid == 0)
        __builtin_amdgcn_fence(__ATOMIC_ACQUIRE, "agent");
      __syncthreads();
    }

    const int wm = wid >> 2, wn = wid & 3;
    const int m0 = mt * 64 + wm * 32;
    bf16x8 areg[2][16];
#pragma unroll
    for (int i = 0; i < 2; ++i)
#pragma unroll
      for (int kk = 0; kk < 16; ++kk)
        areg[i][kk] = *reinterpret_cast<const bf16x8*>(
            P.wh_bf + (size_t)(m0 + i * 16 + lr) * H + kk * 32 + lk);

    for (int nt2 = 0; nt2 < 15; ++nt2) {
      const int n0 = chunk * 3840 + nt2 * 256 + wn * 64;
      f32x4 acc[2][4];
#pragma unroll
      for (int i = 0; i < 2; ++i)
#pragma unroll
        for (int nf = 0; nf < 4; ++nf) acc[i][nf] = (f32x4)0.0f;

#pragma unroll 4
      for (int kk = 0; kk < 16; ++kk) {
        bf16x8 b[4];
#pragma unroll
        for (int nf = 0; nf < 4; ++nf) {
          int n = n0 + nf * 16 + lr;
          bf16x8 bz = (bf16x8)(short)0;
          if (n < VT) bz = *reinterpret_cast<const bf16x8*>(P.Wv_bf + (size_t)n * H + kk * 32 + lk);
          b[nf] = bz;
        }
#pragma unroll
        for (int i = 0; i < 2; ++i)
#pragma unroll
          for (int nf = 0; nf < 4; ++nf)
            acc[i][nf] = __builtin_amdgcn_mfma_f32_16x16x32_bf16(areg[i][kk], b[nf], acc[i][nf], 0, 0, 0);
      }

      float bc[4];
      int val[4];
#pragma unroll
      for (int nf = 0; nf < 4; ++nf) {
        int n = n0 + nf * 16 + lr;
        val[nf] = (n < VT);
        bc[nf] = val[nf] ? P.bv[n] : 0.f;
      }
#pragma unroll
      for (int i = 0; i < 2; ++i) {
#pragma unroll
        for (int jreg = 0; jreg < 4; ++jreg) {
          float lg[4];
          float mx = -3.0e38f;
#pragma unroll
          for (int nf = 0; nf < 4; ++nf) {
            lg[nf] = val[nf] ? (acc[i][nf][jreg] + bc[nf]) : -3.0e38f;
            mx = fmaxf(mx, lg[nf]);
          }
#pragma unroll
          for (int d = 1; d < 16; d <<= 1) mx = fmaxf(mx, __shfl_xor(mx, d));
          float s = 0.f;
#pragma unroll
          for (int nf = 0; nf < 4; ++nf) s += val[nf] ? expf(lg[nf] - mx) : 0.f;
#pragma unroll
          for (int d = 1; d < 16; d <<= 1) s += __shfl_xor(s, d);
          if (lr == 0) {
            int rloc = wm * 32 + i * 16 + (lane >> 4) * 4 + jreg;
            red[wn][rloc][0] = mx;
            red[wn][rloc][1] = s;
          }
        }
      }
      __syncthreads();
      if (tid < 64) {
        int r2 = tid;
        float M = -3.0e38f;
#pragma unroll
        for (int q = 0; q < 4; ++q) M = fmaxf(M, red[q][r2][0]);
        float S = 0.f;
#pragma unroll
        for (int q = 0; q < 4; ++q) S += red[q][r2][1] * expf(red[q][r2][0] - M);
        size_t p = ((size_t)(mt * 64 + r2) * NT2 + chunk * 15 + nt2) * 2;
        P.partials[p] = M;
        P.partials[p + 1] = S;
      }
      __syncthreads();
    }
    return;
  }

  // ================= SEQUENTIAL ROLE (blocks 0..15) =================
  __shared__ f32x4 hred[2][4][64];
  const int gw = bid * 8 + wid;
  uint ph = 0;

  // ---- word encoder: 30 steps, M=320 ----
  {
    float cst[5][4];
#pragma unroll
    for (int it = 0; it < 5; ++it)
#pragma unroll
      for (int rg = 0; rg < 4; ++rg) cst[it][rg] = 0.f;
    ushort* cur = P.h0;
    ushort* nxt = P.h1;
    const int ug = gw & 31;
    const int unit = ug * 16 + lr;
    const ushort* wb = P.weWh + (size_t)(ug * 16 + lr) * H + lk;
    for (int l = 0; l < LL; ++l) {
#pragma unroll
      for (int it = 0; it < 5; ++it) {
        int mt = (gw + it * 128) >> 5;
        f32x4 acc[4];
#pragma unroll
        for (int g = 0; g < 4; ++g) acc[g] = (f32x4)0.0f;
        const ushort* ab = cur + (size_t)(mt * 16 + lr) * H + lk;
#pragma unroll
        for (int k0 = 0; k0 < H; k0 += 32) {
          bf16x8 a = *reinterpret_cast<const bf16x8*>(ab + k0);
#pragma unroll
          for (int g = 0; g < 4; ++g) {
            bf16x8 b = *reinterpret_cast<const bf16x8*>(wb + (size_t)g * H * H + k0);
            acc[g] = __builtin_amdgcn_mfma_f32_16x16x32_bf16(a, b, acc[g], 0, 0, 0);
          }
        }
#pragma unroll
        for (int rg = 0; rg < 4; ++rg) {
          int row = mt * 16 + orow + rg;
          const ushort* xi = P.XiW + (size_t)(l * 320 + row) * 2048 + unit;
          float gi = acc[0][rg] + b2f(xi[0]);
          float gf = acc[1][rg] + b2f(xi[512]);
          float gc = acc[2][rg] + b2f(xi[1024]);
          float go = acc[3][rg] + b2f(xi[1536]);
          float c = sigmoidf_(gf) * cst[it][rg] + sigmoidf_(gi) * tanhf(gc);
          float h = sigmoidf_(go) * tanhf(c);
          cst[it][rg] = c;
          nxt[(size_t)row * H + unit] = f2b_rne(h);
        }
      }
      sbar(P.sflags, bid, UBLK, ++ph);
      ushort* t = cur; cur = nxt; nxt = t;
    }
    // XiS = h30 @ se_Wi^T + se_b (f32)
    {
      const ushort* wbs = P.seWi + (size_t)(ug * 16 + lr) * H + lk;
#pragma unroll
      for (int it = 0; it < 5; ++it) {
        int mt = (gw + it * 128) >> 5;
        f32x4 acc[4];
#pragma unroll
        for (int g = 0; g < 4; ++g) acc[g] = (f32x4)0.0f;
        const ushort* ab = cur + (size_t)(mt * 16 + lr) * H + lk;
#pragma unroll
        for (int k0 = 0; k0 < H; k0 += 32) {
          bf16x8 a = *reinterpret_cast<const bf16x8*>(ab + k0);
#pragma unroll
          for (int g = 0; g < 4; ++g) {
            bf16x8 b = *reinterpret_cast<const bf16x8*>(wbs + (size_t)g * H * H + k0);
            acc[g] = __builtin_amdgcn_mfma_f32_16x16x32_bf16(a, b, acc[g], 0, 0, 0);
          }
        }
#pragma unroll
        for (int rg = 0; rg < 4; ++rg) {
          int row = mt * 16 + orow + rg;
#pragma unroll
          for (int g = 0; g < 4; ++g)
            P.XiS[(size_t)row * 2048 + g * H + unit] = acc[g][rg] + P.se_b[g * H + unit];
        }
      }
    }
    sbar(P.sflags, bid, UBLK, ++ph);
    // XiW is now dead -> release vocab conversion
    if (bid == 0 && tid == 0)
      __hip_atomic_store(P.vflag, 1u, __ATOMIC_RELEASE, SCOPE_AGENT);
  }

  // ---- sentence encoder: 20 steps, M=16 ----
  float cw[4] = {0.f, 0.f, 0.f, 0.f};
  float csd[4] = {0.f, 0.f, 0.f, 0.f};
  {
    float cse[4] = {0.f, 0.f, 0.f, 0.f};
    ushort* cur = P.sh0;
    ushort* nxt = P.sh1;
    const int ug = bid * 2 + wid;        // valid when wid<2
    const int unit = ug * 16 + lr;
    for (int s = 0; s < SS; ++s) {
      if (wid < 2) {
        f32x4 acc[4];
#pragma unroll
        for (int g = 0; g < 4; ++g) acc[g] = (f32x4)0.0f;
        const ushort* ab = cur + (size_t)lr * H + lk;
        const ushort* wb = P.seWh + (size_t)(ug * 16 + lr) * H + lk;
#pragma unroll
        for (int k0 = 0; k0 < H; k0 += 32) {
          bf16x8 a = *reinterpret_cast<const bf16x8*>(ab + k0);
#pragma unroll
          for (int g = 0; g < 4; ++g) {
            bf16x8 b = *reinterpret_cast<const bf16x8*>(wb + (size_t)g * H * H + k0);
            acc[g] = __builtin_amdgcn_mfma_f32_16x16x32_bf16(a, b, acc[g], 0, 0, 0);
          }
        }
#pragma unroll
        for (int rg = 0; rg < 4; ++rg) {
          int row = orow + rg;
          const float* xi = P.XiS + (size_t)(s * 16 + row) * 2048 + unit;
          float gi = acc[0][rg] + xi[0];
          float gf = acc[1][rg] + xi[512];
          float gc = acc[2][rg] + xi[1024];
          float go = acc[3][rg] + xi[1536];
          float c = sigmoidf_(gf) * cse[rg] + sigmoidf_(gi) * tanhf(gc);
          float h = sigmoidf_(go) * tanhf(c);
          cse[rg] = c;
          nxt[(size_t)row * H + unit] = f2b_rne(h);
          P.sent_out[(size_t)(s * 16 + row) * H + unit] = h;
          P.sent_out_bf[(size_t)(s * 16 + row) * H + unit] = f2b_rne(h);
        }
      }
      sbar(P.sflags, bid, UBLK, ++ph);
      ushort* t = cur; cur = nxt; nxt = t;
    }
    if (wid < 2) {
      f32x4 v; v[0] = cse[0]; v[1] = cse[1]; v[2] = cse[2]; v[3] = cse[3];
      hred[wid][0][lane] = v;
#pragma unroll
      for (int rg = 0; rg < 4; ++rg) csd[rg] = cse[rg];
    }
    __syncthreads();
    if (wid < 4 && !(wid & 1)) {
      f32x4 v = hred[wid >> 1][0][lane];
      cw[0] = v[0]; cw[1] = v[1]; cw[2] = v[2]; cw[3] = v[3];
    }
    __syncthreads();
  }

  // ---- sent_feat = sent_out @ W_feat^T + b_feat ----
  {
    const int ug = gw & 31;
    const int unit = ug * 16 + lr;
    const ushort* wb = P.wfeat + (size_t)(ug * 16 + lr) * H + lk;
#pragma unroll
    for (int it = 0; it < 5; ++it) {
      int mt = (gw + it * 128) >> 5;
      f32x4 acc = (f32x4)0.0f;
      const ushort* ab = P.sent_out_bf + (size_t)(mt * 16 + lr) * H + lk;
#pragma unroll
      for (int k0 = 0; k0 < H; k0 += 32) {
        bf16x8 a = *reinterpret_cast<const bf16x8*>(ab + k0);
        bf16x8 b = *reinterpret_cast<const bf16x8*>(wb + k0);
        acc = __builtin_amdgcn_mfma_f32_16x16x32_bf16(a, b, acc, 0, 0, 0);
      }
#pragma unroll
      for (int rg = 0; rg < 4; ++rg) {
        int row = mt * 16 + orow + rg;
        P.sent_feat[(size_t)row * H + unit] = acc[rg] + P.b_feat[unit];
      }
    }
    sbar(P.sflags, bid, UBLK, ++ph);
  }

  // ---- hierarchical decoder ----
  {
    const int half = wid & 1;            // k-half (wid<4)
    const int ug2 = bid * 2 + (wid >> 1);
    const int unit2 = ug2 * 16 + lr;
    const int ug = bid * 2 + wid;        // full-k layout (wid<2)
    const int unit = ug * 16 + lr;

    for (int n = 0; n < NN; ++n) {
      bf16x8 wreg[4][8];
      if (wid < 4) {
#pragma unroll
        for (int g = 0; g < 4; ++g)
#pragma unroll
          for (int kk = 0; kk < 8; ++kk)
            wreg[g][kk] = *reinterpret_cast<const bf16x8*>(
                P.wdWh + (size_t)g * H * H + (size_t)(ug2 * 16 + lr) * H +
                half * 256 + kk * 32 + lk);
      }
      for (int t = 0; t < TT - 1; ++t) {
        int stp = n * (TT - 1) + t;
        f32x4 acc[4];
        if (wid < 4) {
          const ushort* A = (t == 0)
              ? ((n == 0) ? P.sh0 : P.final_bf)
              : P.wh_bf + (size_t)(stp - 1) * 16 * H;
#pragma unroll
          for (int g = 0; g < 4; ++g) acc[g] = (f32x4)0.0f;
          const ushort* ab = A + (size_t)lr * H + half * 256 + lk;
#pragma unroll
          for (int kk = 0; kk < 8; ++kk) {
            bf16x8 a = *reinterpret_cast<const bf16x8*>(ab + kk * 32);
#pragma unroll
            for (int g = 0; g < 4; ++g)
              acc[g] = __builtin_amdgcn_mfma_f32_16x16x32_bf16(a, wreg[g][kk], acc[g], 0, 0, 0);
          }
          if (half) {
#pragma unroll
            for (int g = 0; g < 4; ++g) hred[wid >> 1][g][lane] = acc[g];
          }
        }
        __syncthreads();
        if (wid < 4 && !half) {
#pragma unroll
          for (int g = 0; g < 4; ++g) acc[g] += hred[wid >> 1][g][lane];
#pragma unroll
          for (int rg = 0; rg < 4; ++rg) {
            int row = orow + rg;
            const ushort* xi = P.XiD + (size_t)(stp * 16 + row) * 2048 + unit2;
            float gi = acc[0][rg] + b2f(xi[0]);
            float gf = acc[1][rg] + b2f(xi[512]);
            float gc = acc[2][rg] + b2f(xi[1024]);
            float go = acc[3][rg] + b2f(xi[1536]);
            float c = sigmoidf_(gf) * cw[rg] + sigmoidf_(gi) * tanhf(gc);
            float h = sigmoidf_(go) * tanhf(c);
            cw[rg] = c;
            P.wh_bf[(size_t)(stp * 16 + row) * H + unit2] = f2b_rne(h);
          }
        }
        sbar(P.sflags, bid, UBLK, ++ph);
      }
      // sentence n's wh rows are globally visible -> release vocab tiles
      if (bid == 0 && tid == 0)
        __hip_atomic_store(P.vflag, 2u + (uint)n, __ATOMIC_RELEASE, SCOPE_AGENT);
      // ---- sentence-decoder LSTM step ----
      if (wid < 2) {
        f32x4 acc[4];
#pragma unroll
        for (int g = 0; g < 4; ++g) acc[g] = (f32x4)0.0f;
        const ushort* A1 = P.wh_bf + (size_t)(n * (TT - 1) + TT - 2) * 16 * H;
        const ushort* A2 = (n == 0) ? P.sh0 : P.final_bf;
        const ushort* ab1 = A1 + (size_t)lr * H + lk;
        const ushort* wb1 = P.sdWi + (size_t)(ug * 16 + lr) * H + lk;
#pragma unroll
        for (int k0 = 0; k0 < H; k0 += 32) {
          bf16x8 a = *reinterpret_cast<const bf16x8*>(ab1 + k0);
#pragma unroll
          for (int g = 0; g < 4; ++g) {
            bf16x8 b = *reinterpret_cast<const bf16x8*>(wb1 + (size_t)g * H * H + k0);
            acc[g] = __builtin_amdgcn_mfma_f32_16x16x32_bf16(a, b, acc[g], 0, 0, 0);
          }
        }
        const ushort* ab2 = A2 + (size_t)lr * H + lk;
        const ushort* wb2 = P.sdWh + (size_t)(ug * 16 + lr) * H + lk;
#pragma unroll
        for (int k0 = 0; k0 < H; k0 += 32) {
          bf16x8 a = *reinterpret_cast<const bf16x8*>(ab2 + k0);
#pragma unroll
          for (int g = 0; g < 4; ++g) {
            bf16x8 b = *reinterpret_cast<const bf16x8*>(wb2 + (size_t)g * H * H + k0);
            acc[g] = __builtin_amdgcn_mfma_f32_16x16x32_bf16(a, b, acc[g], 0, 0, 0);
          }
        }
#pragma unroll
        for (int rg = 0; rg < 4; ++rg) {
          int row = orow + rg;
          float gi = acc[0][rg] + P.sd_b[0 * H + unit];
          float gf = acc[1][rg] + P.sd_b[1 * H + unit];
          float gc = acc[2][rg] + P.sd_b[2 * H + unit];
          float go = acc[3][rg] + P.sd_b[3 * H + unit];
          float c = sigmoidf_(gf) * csd[rg] + sigmoidf_(gi) * tanhf(gc);
          float h = sigmoidf_(go) * tanhf(c);
          csd[rg] = c;
          P.sdh_bf[(size_t)row * H + unit] = f2b_rne(h);
        }
      }
      sbar(P.sflags, bid, UBLK, ++ph);
      // ---- qb = sdh @ attn_Wh^T ----
      if (wid < 2) {
        f32x4 acc = (f32x4)0.0f;
        const ushort* ab = P.sdh_bf + (size_t)lr * H + lk;
        const ushort* wb = P.attnWh + (size_t)(ug * 16 + lr) * H + lk;
#pragma unroll
        for (int k0 = 0; k0 < H; k0 += 32) {
          bf16x8 a = *reinterpret_cast<const bf16x8*>(ab + k0);
          bf16x8 b = *reinterpret_cast<const bf16x8*>(wb + k0);
          acc = __builtin_amdgcn_mfma_f32_16x16x32_bf16(a, b, acc, 0, 0, 0);
        }
#pragma unroll
        for (int rg = 0; rg < 4; ++rg)
          P.qb[(size_t)(orow + rg) * H + unit] = acc[rg];
      }
      sbar(P.sflags, bid, UBLK, ++ph);
      // ---- e[s,b] ----
      for (int sb = gw; sb < 320; sb += 128) {
        int b = sb & 15;
        float cov = P.covb[sb];
        float sum = 0.f;
        for (int h2 = lane; h2 < H; h2 += 64)
          sum += tanhf(P.sent_feat[(size_t)sb * H + h2] + P.qb[b * H + h2] +
                       cov * P.attn_wc[h2]) * P.attn_v[h2];
#pragma unroll
        for (int d = 1; d < 64; d <<= 1) sum += __shfl_xor(sum, d);
        if (lane == 0)
          P.ebuf[sb] = (P.articles[sb * LL] > 0) ? sum : -1e9f;
      }
      sbar(P.sflags, bid, UBLK, ++ph);
      // ---- softmax over s + coverage (block bid owns batch col b = bid) ----
      if (wid == 0) {
        int b = bid;
        float ev = (lane < SS) ? P.ebuf[lane * 16 + b] : -3.0e38f;
        float mx = ev;
#pragma unroll
        for (int d = 1; d < 64; d <<= 1) mx = fmaxf(mx, __shfl_xor(mx, d));
        float ex = (lane < SS) ? expf(ev - mx) : 0.f;
        float s = ex;
#pragma unroll
        for (int d = 1; d < 64; d <<= 1) s += __shfl_xor(s, d);
        float al = ex / s;
        float cl = 0.f;
        if (lane < SS) {
          int sb = lane * 16 + b;
          float cov = P.covb[sb];
          cl = fminf(al, cov);
          P.covb[sb] = cov + al;
          P.alignb[sb] = al;
        }
#pragma unroll
        for (int d = 1; d < 64; d <<= 1) cl += __shfl_xor(cl, d);
        if (lane == 0) atomicAdd(P.loss, cl * (1.f / BB));
      }
      __syncthreads();   // softmax col b=bid is block-local to context below
      // ---- context + catb = [ctx | sdh] for batch col b = bid ----
      {
        int b = bid, h2 = tid;
        float s = 0.f;
#pragma unroll
        for (int ss2 = 0; ss2 < SS; ++ss2)
          s += P.alignb[ss2 * 16 + b] * P.sent_out[(size_t)(ss2 * 16 + b) * H + h2];
        P.catb[b * 1024 + h2] = f2b_rne(s);
        P.catb[b * 1024 + 512 + h2] = P.sdh_bf[(size_t)b * H + h2];
      }
      sbar(P.sflags, bid, UBLK, ++ph);
      // ---- final = tanh(catb @ W_out^T + b_out) ----
      if (wid < 2) {
        f32x4 acc = (f32x4)0.0f;
        const ushort* ab = P.catb + (size_t)lr * 1024 + lk;
        const ushort* wb = P.Wout + (size_t)(ug * 16 + lr) * 1024 + lk;
#pragma unroll
        for (int k0 = 0; k0 < 1024; k0 += 32) {
          bf16x8 a = *reinterpret_cast<const bf16x8*>(ab + k0);
          bf16x8 b = *reinterpret_cast<const bf16x8*>(wb + k0);
          acc = __builtin_amdgcn_mfma_f32_16x16x32_bf16(a, b, acc, 0, 0, 0);
        }
#pragma unroll
        for (int rg = 0; rg < 4; ++rg) {
          int row = orow + rg;
          float v = tanhf(acc[rg] + P.b_out[unit]);
          P.final_bf[(size_t)row * H + unit] = f2b_rne(v);
        }
      }
      sbar(P.sflags, bid, UBLK, ++ph);
    }
    // final release so lagging vocab tiles can't miss sentence 5
    if (bid == 0 && tid == 0)
      __hip_atomic_store(P.vflag, 7u, __ATOMIC_RELEASE, SCOPE_AGENT);
  }
}

// target logit per decoder row (consistent bf16 operands)
__global__ void tlog_kernel(const ushort* __restrict__ wh_bf,
                            const ushort* __restrict__ Wv_bf,
                            const float* __restrict__ bv,
                            const int* __restrict__ summaries,
                            float* __restrict__ tlog)
{
  int row = blockIdx.x;
  int lane = threadIdx.x;
  int b = row & 15, stp = row >> 4;
  int n = stp / (TT - 1), t = stp % (TT - 1);
  int tgt = summaries[(n * BB + b) * TT + t + 1];
  float s = 0.f;
  for (int k = lane; k < H; k += 64)
    s += b2f(wh_bf[(size_t)row * H + k]) * b2f(Wv_bf[(size_t)tgt * H + k]);
#pragma unroll
  for (int d = 1; d < 64; d <<= 1) s += __shfl_xor(s, d);
  if (lane == 0) tlog[row] = s + bv[tgt];
}

// per-step masked-mean NLL from partials
__global__ __launch_bounds__(256) void nll_kernel(
    const float* __restrict__ partials, const float* __restrict__ tlog,
    const int* __restrict__ summaries, float* __restrict__ loss)
{
  int stp = blockIdx.x;
  int tid = threadIdx.x;
  int rr = tid >> 4, ch = tid & 15;
  int row = stp * 16 + rr;
  const float* pr = partials + (size_t)row * NT2 * 2;
  float mx = -3.0e38f;
  for (int t2 = ch; t2 < NT2; t2 += 16) mx = fmaxf(mx, pr[t2 * 2]);
#pragma unroll
  for (int d = 1; d < 16; d <<= 1) mx = fmaxf(mx, __shfl_xor(mx, d));
  float s = 0.f;
  for (int t2 = ch; t2 < NT2; t2 += 16) s += pr[t2 * 2 + 1] * expf(pr[t2 * 2] - mx);
#pragma unroll
  for (int d = 1; d < 16; d <<= 1) s += __shfl_xor(s, d);
  __shared__ float sh_n[16], sh_m[16];
  if (ch == 0) {
    float lse = mx + logf(s);
    float nll = lse - tlog[row];
    int b = row & 15;
    int n = stp / (TT - 1), t = stp % (TT - 1);
    int wa = summaries[(n * BB + b) * TT + t + 1];
    sh_n[rr] = (wa != 0) ? nll : 0.f;
    sh_m[rr] = (wa != 0) ? 1.f : 0.f;
  }
  __syncthreads();
  if (tid == 0) {
    float sn = 0.f, sm = 0.f;
    for (int r2 = 0; r2 < 16; ++r2) { sn += sh_n[r2]; sm += sh_m[r2]; }
    atomicAdd(loss, sn / fmaxf(sm, 1.f));
  }
}

// ---------------------------------------------------------------------------
extern "C" void kernel_launch(void* const* d_in, const int* in_sizes, int n_in,
                              void* d_out, int out_size, void* d_ws, size_t ws_size,
                              hipStream_t stream)
{
  (void)in_sizes; (void)n_in; (void)out_size; (void)ws_size;
  const int*   articles  = (const int*)d_in[0];
  const int*   summaries = (const int*)d_in[1];
  const float* emb_src   = (const float*)d_in[2];
  const float* emb_tgt   = (const float*)d_in[3];
  const float* we_Wi = (const float*)d_in[4];
  const float* we_Wh = (const float*)d_in[5];
  const float* we_b  = (const float*)d_in[6];
  const float* se_Wi = (const float*)d_in[7];
  const float* se_Wh = (const float*)d_in[8];
  const float* se_b  = (const float*)d_in[9];
  const float* W_feat = (const float*)d_in[10];
  const float* b_feat = (const float*)d_in[11];
  const float* wd_Wi = (const float*)d_in[12];
  const float* wd_Wh = (const float*)d_in[13];
  const float* wd_b  = (const float*)d_in[14];
  const float* W_vocab = (const float*)d_in[15];
  const float* b_vocab = (const float*)d_in[16];
  const float* sd_Wi = (const float*)d_in[17];
  const float* sd_Wh = (const float*)d_in[18];
  const float* sd_b  = (const float*)d_in[19];
  const float* attn_Wh = (const float*)d_in[20];
  const float* attn_wc = (const float*)d_in[21];
  const float* attn_v  = (const float*)d_in[22];
  const float* W_out = (const float*)d_in[23];
  const float* b_out = (const float*)d_in[24];

  char* wsb = (char*)d_ws;
  size_t off = 0;
  auto alloc = [&](size_t bytes) -> char* {
    char* p = wsb + off;
    off += (bytes + 255) & ~(size_t)255;
    return p;
  };

  // regA: A_we (prep->proj) UNION {wh_bf, partials, tlog} (mega onwards)
  char* regA = alloc(9830400);
  ushort* A_we     = (ushort*)regA;
  ushort* wh_bf    = (ushort*)regA;                    // 1856*512*2
  float*  partials = (float*)(regA + 1900544);         // 1856*120*2*4
  float*  tlogb    = (float*)(regA + 3682304);         // 1824*4

  ushort* A_wd = (ushort*)alloc((size_t)MROWS * H * 2);

  // regW: XiW bf16 (proj->mega word-enc) UNION Wv_bf (vocab role)
  char* regW = alloc((size_t)9600 * 2048 * 2);
  ushort* XiW   = (ushort*)regW;
  ushort* Wv_bf = (ushort*)regW;

  ushort* XiD = (ushort*)alloc((size_t)MROWS * 2048 * 2);

  ushort* weWi  = (ushort*)alloc(4 * H * H * 2);
  ushort* wdWi  = (ushort*)alloc(4 * H * H * 2);
  ushort* weWh  = (ushort*)alloc(4 * H * H * 2);
  ushort* seWi  = (ushort*)alloc(4 * H * H * 2);
  ushort* seWh  = (ushort*)alloc(4 * H * H * 2);
  ushort* wdWh  = (ushort*)alloc(4 * H * H * 2);
  ushort* sdWi  = (ushort*)alloc(4 * H * H * 2);
  ushort* sdWh  = (ushort*)alloc(4 * H * H * 2);
  ushort* wfeat = (ushort*)alloc(H * H * 2);
  ushort* attnWh= (ushort*)alloc(H * H * 2);
  ushort* Wout  = (ushort*)alloc(H * 2 * H * 2);

  float*  XiS = (float*)alloc((size_t)320 * 2048 * 4);
  ushort* h0  = (ushort*)alloc(320 * H * 2);
  ushort* h1  = (ushort*)alloc(320 * H * 2);
  ushort* sh0 = (ushort*)alloc(16 * H * 2);
  ushort* sh1 = (ushort*)alloc(16 * H * 2);
  float*  sent_out    = (float*)alloc(320 * H * 4);
  ushort* sent_out_bf = (ushort*)alloc(320 * H * 2);
  float*  sent_feat   = (float*)alloc(320 * H * 4);
  ushort* sdh_bf   = (ushort*)alloc(16 * H * 2);
  ushort* final_bf = (ushort*)alloc(16 * H * 2);
  ushort* catb     = (ushort*)alloc(16 * 1024 * 2);
  float*  qb       = (float*)alloc(16 * H * 4);
  float*  ebuf   = (float*)alloc(1280);
  float*  alignb = (float*)alloc(1280);
  float*  covb   = (float*)alloc(1280);
  uint*   sflags  = (uint*)alloc(UBLK * 16 * 4);
  uint*   vbflags = (uint*)alloc(NV * 16 * 4);
  uint*   vflag   = (uint*)alloc(256);

  float* loss = (float*)d_out;
  hipMemsetAsync(loss, 0, 4, stream);
  hipMemsetAsync(covb, 0, 1280, stream);
  hipMemsetAsync(h0, 0, 320 * H * 2, stream);
  hipMemsetAsync(sh0, 0, 16 * H * 2, stream);
  hipMemsetAsync(sflags, 0, UBLK * 16 * 4, stream);
  hipMemsetAsync(vbflags, 0, NV * 16 * 4, stream);
  hipMemsetAsync(vflag, 0, 256, stream);

  // 1) prep: gathers + weight conversions
  {
    PrepP P = {articles, summaries, emb_src, emb_tgt,
               we_Wi, wd_Wi, we_Wh, se_Wi, se_Wh, W_feat,
               wd_Wh, sd_Wi, sd_Wh, attn_Wh, W_out,
               A_we, A_wd, weWi, wdWi, weWh, seWi, seWh, wfeat,
               wdWh, sdWi, sdWh, attnWh, Wout};
    prep_kernel<<<2048, 256, 0, stream>>>(P);
  }

  // 2) input projections
  proj_mfma_kernel<<<1432, 512, 0, stream>>>(A_we, weWi, we_b, XiW,
                                             A_wd, wdWi, wd_b, XiD);

  // zero wh_bf pad rows (A_we dead after proj; stream-ordered)
  hipMemsetAsync((char*)wh_bf + (size_t)MROWS * H * 2, 0,
                 (size_t)(MPAD - MROWS) * H * 2, stream);

  // 3) MEGA: sequential chain (16 blocks) + concurrent vocab/heater (232)
  {
    MP P;
    P.XiW = XiW; P.XiD = XiD;
    P.weWh = weWh; P.seWi = seWi; P.seWh = seWh; P.wfeat = wfeat;
    P.wdWh = wdWh; P.sdWi = sdWi; P.sdWh = sdWh; P.attnWh = attnWh; P.Wout = Wout;
    P.se_b = se_b; P.b_feat = b_feat; P.sd_b = sd_b; P.b_out = b_out;
    P.attn_wc = attn_wc; P.attn_v = attn_v; P.articles = articles;
    P.h0 = h0; P.h1 = h1; P.XiS = XiS; P.sh0 = sh0; P.sh1 = sh1;
    P.sent_out = sent_out; P.sent_out_bf = sent_out_bf; P.sent_feat = sent_feat;
    P.wh_bf = wh_bf; P.sdh_bf = sdh_bf; P.final_bf = final_bf; P.catb = catb;
    P.qb = qb; P.ebuf = ebuf; P.alignb = alignb; P.covb = covb; P.loss = loss;
    P.sflags = sflags; P.vbflags = vbflags; P.vflag = vflag;
    P.Wv = W_vocab; P.Wv_bf = Wv_bf; P.bv = b_vocab; P.partials = partials;
    mega_kernel<<<MEGA, 512, 0, stream>>>(P);
  }

  // 4) target logits + NLL
  tlog_kernel<<<MROWS, 64, 0, stream>>>(wh_bf, Wv_bf, b_vocab, summaries, tlogb);
  nll_kernel<<<NSTEPS, 256, 0, stream>>>(partials, tlogb, summaries, loss);
}